// Round 4
// baseline (2777.783 us; speedup 1.0000x reference)
//
#include <hip/hip_runtime.h>
#include <math.h>

#define SCOPE_AGENT __HIP_MEMORY_SCOPE_AGENT
#define SCOPE_SYS   __HIP_MEMORY_SCOPE_SYSTEM

__device__ __forceinline__ float sigf(float x) { return 1.0f / (1.0f + expf(-x)); }
__device__ __forceinline__ float4 f4add(float4 a, float4 b) {
  return make_float4(a.x + b.x, a.y + b.y, a.z + b.z, a.w + b.w);
}
__device__ __forceinline__ float4 f4fma(float s, float4 b, float4 a) {
  return make_float4(fmaf(s, b.x, a.x), fmaf(s, b.y, a.y), fmaf(s, b.z, a.z), fmaf(s, b.w, a.w));
}
// agent-scope (sc1) 8B load: bypasses non-coherent per-XCD L2 (coherent at LLC)
__device__ __forceinline__ float2 ld2a(const float* p) {
  unsigned long long v = __hip_atomic_load((unsigned long long*)p, __ATOMIC_RELAXED, SCOPE_AGENT);
  union { unsigned long long u; float2 f; } c; c.u = v; return c.f;
}
__device__ __forceinline__ void st1a(float* p, float v) {
  __hip_atomic_store(p, v, __ATOMIC_RELAXED, SCOPE_AGENT);
}

// ---------------- Encoder GEMM1: C = relu(X @ W + b) ----------------
__global__ __launch_bounds__(256) void k_gemm1(const float* __restrict__ X,
                                               const float* __restrict__ W,
                                               const float* __restrict__ Bv,
                                               float* __restrict__ C)
{
  const int K = 1024, N = 512;
  __shared__ float As[8][132];
  __shared__ float Bs[8][132];
  int tid = threadIdx.x;
  int bm = blockIdx.x >> 2;
  int bn = blockIdx.x & 3;
  int tx = tid & 15, ty = tid >> 4;
  int arow = tid >> 1, acol4 = (tid & 1) * 4;
  int bkk = tid >> 5, bn4 = (tid & 31) * 4;
  const float* Xb = X + (size_t)(bm * 128) * K;
  const float* Wb = W + bn * 128;
  float acc[8][8];
#pragma unroll
  for (int i = 0; i < 8; i++)
#pragma unroll
    for (int j2 = 0; j2 < 8; j2++) acc[i][j2] = 0.f;
  for (int k0 = 0; k0 < K; k0 += 8) {
    float4 av = *(const float4*)(Xb + (size_t)arow * K + k0 + acol4);
    float4 bv = *(const float4*)(Wb + (size_t)(k0 + bkk) * N + bn4);
    As[acol4 + 0][arow] = av.x;
    As[acol4 + 1][arow] = av.y;
    As[acol4 + 2][arow] = av.z;
    As[acol4 + 3][arow] = av.w;
    *(float4*)(&Bs[bkk][bn4]) = bv;
    __syncthreads();
#pragma unroll
    for (int kk = 0; kk < 8; kk++) {
      float a[8], b[8];
      *(float4*)(a)     = *(const float4*)(&As[kk][ty * 8]);
      *(float4*)(a + 4) = *(const float4*)(&As[kk][ty * 8 + 4]);
      *(float4*)(b)     = *(const float4*)(&Bs[kk][tx * 8]);
      *(float4*)(b + 4) = *(const float4*)(&Bs[kk][tx * 8 + 4]);
#pragma unroll
      for (int i = 0; i < 8; i++)
#pragma unroll
        for (int j2 = 0; j2 < 8; j2++) acc[i][j2] = fmaf(a[i], b[j2], acc[i][j2]);
    }
    __syncthreads();
  }
  int crow0 = bm * 128 + ty * 8;
  int ccol0 = bn * 128 + tx * 8;
#pragma unroll
  for (int i = 0; i < 8; i++)
#pragma unroll
    for (int j2 = 0; j2 < 8; j2++) {
      float v = acc[i][j2] + Bv[ccol0 + j2];
      C[(size_t)(crow0 + i) * N + ccol0 + j2] = v > 0.f ? v : 0.f;
    }
}

// ---------------- Encoder GEMM2 ----------------
__global__ __launch_bounds__(256) void k_gemm2(const float* __restrict__ A,
                                               const float* __restrict__ W,
                                               const float* __restrict__ Bv,
                                               float* __restrict__ zp)
{
  const int K = 512, N = 128;
  __shared__ float As[8][132];
  __shared__ float Bs[8][132];
  int tid = threadIdx.x;
  int bm = blockIdx.x;
  int tx = tid & 15, ty = tid >> 4;
  int arow = tid >> 1, acol4 = (tid & 1) * 4;
  int bkk = tid >> 5, bn4 = (tid & 31) * 4;
  const float* Ab = A + (size_t)(bm * 128) * K;
  float acc[8][8];
#pragma unroll
  for (int i = 0; i < 8; i++)
#pragma unroll
    for (int j2 = 0; j2 < 8; j2++) acc[i][j2] = 0.f;
  for (int k0 = 0; k0 < K; k0 += 8) {
    float4 av = *(const float4*)(Ab + (size_t)arow * K + k0 + acol4);
    float4 bv = *(const float4*)(W + (size_t)(k0 + bkk) * N + bn4);
    As[acol4 + 0][arow] = av.x;
    As[acol4 + 1][arow] = av.y;
    As[acol4 + 2][arow] = av.z;
    As[acol4 + 3][arow] = av.w;
    *(float4*)(&Bs[bkk][bn4]) = bv;
    __syncthreads();
#pragma unroll
    for (int kk = 0; kk < 8; kk++) {
      float a[8], b[8];
      *(float4*)(a)     = *(const float4*)(&As[kk][ty * 8]);
      *(float4*)(a + 4) = *(const float4*)(&As[kk][ty * 8 + 4]);
      *(float4*)(b)     = *(const float4*)(&Bs[kk][tx * 8]);
      *(float4*)(b + 4) = *(const float4*)(&Bs[kk][tx * 8 + 4]);
#pragma unroll
      for (int i = 0; i < 8; i++)
#pragma unroll
        for (int j2 = 0; j2 < 8; j2++) acc[i][j2] = fmaf(a[i], b[j2], acc[i][j2]);
    }
    __syncthreads();
  }
  int ccol0 = tx * 8;
#pragma unroll
  for (int i = 0; i < 8; i++) {
    int r = bm * 128 + ty * 8 + i;
    int b = r >> 5, tt = r & 31;
#pragma unroll
    for (int j2 = 0; j2 < 8; j2++) {
      zp[(size_t)b * (33 * 128) + tt * 128 + ccol0 + j2] = acc[i][j2] + Bv[ccol0 + j2];
    }
  }
}

// ---------------- Gram + softmax precompute ----------------
__global__ __launch_bounds__(256) void k_gram(const float* __restrict__ zp,
                                              float* __restrict__ warr,
                                              float* __restrict__ wc,
                                              const float* __restrict__ cgp,
                                              const float* __restrict__ cbp)
{
  __shared__ float zl[32][128];
  __shared__ float sg[32][32];
  int b = blockIdx.x, tid = threadIdx.x;
  const float* zb = zp + (size_t)b * (33 * 128);
  for (int i = tid; i < 32 * 128; i += 256) (&zl[0][0])[i] = zb[i];
  __syncthreads();
  for (int p = tid; p < 496; p += 256) {
    int t = 1;
    while (p >= t * (t + 1) / 2) t++;
    int tp = p - t * (t - 1) / 2;
    const float* za = &zl[t][0];
    const float* zc = &zl[tp][0];
    float s = 0.f;
#pragma unroll 4
    for (int c = 0; c < 128; c += 4) {
      s += za[c] * zc[c] + za[c + 1] * zc[c + 1] + za[c + 2] * zc[c + 2] + za[c + 3] * zc[c + 3];
    }
    sg[t][tp] = s;
  }
  __syncthreads();
  if (tid >= 1 && tid < 32) {
    int t = tid;
    float cg = cgp[0], cb = cbp[0];
    float m = -3.0e38f;
    for (int tp = 0; tp < t; tp++) m = fmaxf(m, sg[t][tp]);
    float se = 0.f;
    for (int tp = 0; tp < t; tp++) se += expf(sg[t][tp] - m);
    float inv = 1.0f / se;
    float wcs = 0.f;
    for (int tp = 0; tp < t; tp++) {
      float s = sg[t][tp];
      float w = expf(s - m) * inv;
      warr[(size_t)b * 1024 + t * 32 + tp] = w;
      wcs = fmaf(w, sigf(fmaf(s, cg, cb)), wcs);
    }
    wc[b * 32 + t] = wcs;
  }
}

// ---------------- flag zeroing ----------------
__global__ __launch_bounds__(1024) void k_zero(int* __restrict__ f)
{
  int i = threadIdx.x;
  if (i < 1024) __hip_atomic_store(&f[i], 0, __ATOMIC_RELAXED, SCOPE_SYS);
}

// ---------------- persistent cooperative scan ----------------
// 512 WGs x 256 thr = 2 WGs/CU. WG -> (rt = wg>>4 [32 rings of 16 rows], cid = wg&15).
// Per step: G phase (gates 16r x 32hc x3g) -> gflag; U phase (keyw 16r x 16c + gate +
// keyr update) -> uflag. Ring-local flag sync only; h/keyrT via agent-scope (sc1) ops.
__global__ __launch_bounds__(256, 2) void k_scan(
    const float* __restrict__ Wx, const float* __restrict__ lb,
    const float* __restrict__ kW, const float* __restrict__ kb,
    const float* __restrict__ gW, const float* __restrict__ gb,
    const float* __restrict__ yW, const float* __restrict__ yb,
    const float* __restrict__ warr, const float* __restrict__ wc,
    float* __restrict__ Mk, float* __restrict__ keyrT, float* __restrict__ h,
    int* __restrict__ gfl, int* __restrict__ ufl, float* __restrict__ out)
{
  __shared__ float smem[14032];
  float* gWs = smem;          // [512] persistent
  float* lbs = smem + 512;    // [96]  persistent (i/c/o bias for this cid's 32 hc)
  float* kbs = smem + 608;    // [16]  persistent
  float* As  = smem + 640;    // G: [32][20] keyr chunk (k-major, 16 rows)
  float* Bs  = smem + 1280;   // G: [32][100] Wx chunk {i,c,o}
  float* Rb  = smem + 640;    // G reduction: [128][52]
  float* hsT = smem + 640;    // U: [512][20] h transposed (quad-rotated rows)
  float* kWs = smem + 10880;  // U: [32][20] kW chunk
  float* RbU = smem + 10880;  // U reduction: [128][20] (after kWs dead)
  float* wws = smem + 13440;  // U: [16][36] softmax weights
  float* gsh = smem + 14016;  // U: [16] gates

  const int tid = threadIdx.x;
  const int wg = blockIdx.x;
  const int rt = wg >> 4, cid = wg & 15;
  const int row0 = rt * 16, hc0 = cid * 32, c0 = cid * 16;

  // persistent preloads
  for (int i = tid; i < 512; i += 256) gWs[i] = gW[i];
  if (tid < 96) {
    int g = tid >> 5, j = tid & 31;
    int ofs = (g == 0) ? 0 : ((g == 1) ? 1024 : 1536);
    lbs[tid] = lb[ofs + hc0 + j];
  }
  if (tid < 16) kbs[tid] = kb[c0 + tid];
  __syncthreads();

  const int ksub = tid >> 5, pos = tid & 31, rg = pos >> 3, cg = pos & 7;

  for (int t = 0; t <= 32; ++t) {
    // =================== G phase ===================
    if (t > 0) {
      if (tid < 16) {
        while (__hip_atomic_load(&ufl[rt * 16 + tid], __ATOMIC_RELAXED, SCOPE_SYS) < t)
          __builtin_amdgcn_s_sleep(2);
      }
      __syncthreads();
      float4 aI[4], aC[4], aO[4];
#pragma unroll
      for (int r = 0; r < 4; r++) {
        aI[r] = make_float4(0.f, 0.f, 0.f, 0.f);
        aC[r] = make_float4(0.f, 0.f, 0.f, 0.f);
        aO[r] = make_float4(0.f, 0.f, 0.f, 0.f);
      }
      for (int c = 0; c < 8; ++c) {
        const int k0 = c * 32;
        if (c) __syncthreads();
        if (tid < 128) {  // stage keyr chunk (sc1 reads)
          const int kkA = tid >> 2, lA = (tid & 3) * 4;
          const float* src = keyrT + (size_t)(k0 + kkA) * 512 + row0 + lA;
          float2 v0 = ld2a(src), v1 = ld2a(src + 2);
          float* d = &As[kkA * 20 + lA];
          d[0] = v0.x; d[1] = v0.y; d[2] = v1.x; d[3] = v1.y;
        }
        {  // stage Wx chunk (plain, L2-resident)
          const int kkB = tid >> 3, lB = (tid & 7) * 4;
          const float* wrow = Wx + (size_t)(k0 + kkB) * 2048;
          float4 b0 = *(const float4*)(wrow + hc0 + lB);
          float4 b1 = *(const float4*)(wrow + 1024 + hc0 + lB);
          float4 b2 = *(const float4*)(wrow + 1536 + hc0 + lB);
          *(float4*)&Bs[kkB * 100 + lB] = b0;
          *(float4*)&Bs[kkB * 100 + 32 + lB] = b1;
          *(float4*)&Bs[kkB * 100 + 64 + lB] = b2;
        }
        __syncthreads();
#pragma unroll
        for (int i = 0; i < 4; ++i) {
          const int kk = ksub * 4 + i;
          float4 a4 = *(const float4*)&As[kk * 20 + rg * 4];
          float4 bI = *(const float4*)&Bs[kk * 100 + cg * 4];
          float4 bC = *(const float4*)&Bs[kk * 100 + 32 + cg * 4];
          float4 bO = *(const float4*)&Bs[kk * 100 + 64 + cg * 4];
          aI[0] = f4fma(a4.x, bI, aI[0]); aC[0] = f4fma(a4.x, bC, aC[0]); aO[0] = f4fma(a4.x, bO, aO[0]);
          aI[1] = f4fma(a4.y, bI, aI[1]); aC[1] = f4fma(a4.y, bC, aC[1]); aO[1] = f4fma(a4.y, bO, aO[1]);
          aI[2] = f4fma(a4.z, bI, aI[2]); aC[2] = f4fma(a4.z, bC, aC[2]); aO[2] = f4fma(a4.z, bO, aO[2]);
          aI[3] = f4fma(a4.w, bI, aI[3]); aC[3] = f4fma(a4.w, bC, aC[3]); aO[3] = f4fma(a4.w, bO, aO[3]);
        }
      }
      if (ksub == 0) {  // tail k = 256
        const float* src = keyrT + (size_t)256 * 512 + row0 + rg * 4;
        float2 v0 = ld2a(src), v1 = ld2a(src + 2);
        float a4[4] = {v0.x, v0.y, v1.x, v1.y};
        const float* wrow = Wx + (size_t)256 * 2048;
        float4 bI = *(const float4*)(wrow + hc0 + cg * 4);
        float4 bC = *(const float4*)(wrow + 1024 + hc0 + cg * 4);
        float4 bO = *(const float4*)(wrow + 1536 + hc0 + cg * 4);
#pragma unroll
        for (int r = 0; r < 4; r++) {
          aI[r] = f4fma(a4[r], bI, aI[r]);
          aC[r] = f4fma(a4[r], bC, aC[r]);
          aO[r] = f4fma(a4[r], bO, aO[r]);
        }
      }
      __syncthreads();
      // 8-way k-split reduction (tree to tid<32)
      for (int half = 128; half >= 32; half >>= 1) {
        if (tid >= half && tid < 2 * half) {
          float* w = &Rb[(tid - half) * 52];
#pragma unroll
          for (int r = 0; r < 4; r++) {
            *(float4*)&w[r * 12] = aI[r];
            *(float4*)&w[r * 12 + 4] = aC[r];
            *(float4*)&w[r * 12 + 8] = aO[r];
          }
        }
        __syncthreads();
        if (tid < half) {
          const float* p = &Rb[tid * 52];
#pragma unroll
          for (int r = 0; r < 4; r++) {
            aI[r] = f4add(aI[r], *(const float4*)&p[r * 12]);
            aC[r] = f4add(aC[r], *(const float4*)&p[r * 12 + 4]);
            aO[r] = f4add(aO[r], *(const float4*)&p[r * 12 + 8]);
          }
        }
        __syncthreads();
      }
      if (tid < 32) {
        float* w = &Rb[tid * 52];
#pragma unroll
        for (int r = 0; r < 4; r++) {
          *(float4*)&w[r * 12] = aI[r];
          *(float4*)&w[r * 12 + 4] = aC[r];
          *(float4*)&w[r * 12 + 8] = aO[r];
        }
      }
      __syncthreads();
#pragma unroll
      for (int u = 0; u < 2; ++u) {  // redistribute + activate + h store (sc1)
        const int e = tid * 2 + u;
        const int hc = e & 31, row = e >> 5;
        const int p = ((row >> 2) * 8 + (hc >> 2)) * 52 + (row & 3) * 12 + (hc & 3);
        float iv = Rb[p] + lbs[hc];
        float cv = Rb[p + 4] + lbs[32 + hc];
        float ov = Rb[p + 8] + lbs[64 + hc];
        float cn = sigf(iv) * tanhf(cv);
        st1a(&h[(size_t)(row0 + row) * 512 + hc0 + hc], sigf(ov) * tanhf(cn));
      }
    } else {  // t == 0: h = act(bias)
#pragma unroll
      for (int u = 0; u < 2; ++u) {
        const int e = tid * 2 + u;
        const int hc = e & 31, row = e >> 5;
        float cn = sigf(lbs[hc]) * tanhf(lbs[32 + hc]);
        st1a(&h[(size_t)(row0 + row) * 512 + hc0 + hc], sigf(lbs[64 + hc]) * tanhf(cn));
      }
    }
    __syncthreads();
    if (tid == 0) {
      __builtin_amdgcn_fence(__ATOMIC_RELEASE, "agent");
      __hip_atomic_store(&gfl[rt * 16 + cid], t + 1, __ATOMIC_RELAXED, SCOPE_SYS);
    }

    // =================== U phase ===================
    if (t < 32) {
      if (tid < 16) {
        while (__hip_atomic_load(&gfl[rt * 16 + tid], __ATOMIC_RELAXED, SCOPE_SYS) < t + 1)
          __builtin_amdgcn_s_sleep(2);
      }
      __syncthreads();
      {  // stage h transposed (sc1) with quad-rotation to spread banks; + wws
        const int r = tid >> 4, seg = tid & 15;
        const int rot = ((seg & 3) << 2);
        const float* hrow = h + (size_t)(row0 + r) * 512 + seg * 32;
#pragma unroll
        for (int i = 0; i < 8; ++i) {
          float2 v0 = ld2a(hrow + i * 4), v1 = ld2a(hrow + i * 4 + 2);
          const int kbase = seg * 32 + i * 4;
          hsT[(kbase + 0) * 20 + ((r + rot) & 15)] = v0.x;
          hsT[(kbase + 1) * 20 + ((r + rot) & 15)] = v0.y;
          hsT[(kbase + 2) * 20 + ((r + rot) & 15)] = v1.x;
          hsT[(kbase + 3) * 20 + ((r + rot) & 15)] = v1.y;
        }
        wws[r * 36 + seg] = (seg < t) ? warr[(size_t)(row0 + r) * 1024 + t * 32 + seg] : 0.f;
        wws[r * 36 + 16 + seg] = (16 + seg < t) ? warr[(size_t)(row0 + r) * 1024 + t * 32 + 16 + seg] : 0.f;
      }
      __syncthreads();
      // keyw GEMM: 16-way k-split, micro 4r x 4c
      const int ksu = tid >> 4, pu = tid & 15, rgu = pu >> 2, cgu = pu & 3;
      float4 au[4];
#pragma unroll
      for (int r = 0; r < 4; r++) au[r] = make_float4(0.f, 0.f, 0.f, 0.f);
      for (int c = 0; c < 16; ++c) {
        if (c) __syncthreads();
        if (tid < 128) {
          const int kkA = tid >> 2, lA = (tid & 3) * 4;
          *(float4*)&kWs[kkA * 20 + lA] = *(const float4*)&kW[(size_t)(c * 32 + kkA) * 256 + c0 + lA];
        }
        __syncthreads();
        const int q = ((rgu + (c & 3)) & 3) << 2;
#pragma unroll
        for (int i = 0; i < 2; ++i) {
          const int kk = ksu * 2 + i;
          float4 a4 = *(const float4*)&hsT[(c * 32 + kk) * 20 + q];
          float4 b4 = *(const float4*)&kWs[kk * 20 + cgu * 4];
          au[0] = f4fma(a4.x, b4, au[0]);
          au[1] = f4fma(a4.y, b4, au[1]);
          au[2] = f4fma(a4.z, b4, au[2]);
          au[3] = f4fma(a4.w, b4, au[3]);
        }
      }
      __syncthreads();
      for (int half = 128; half >= 16; half >>= 1) {
        if (tid >= half && tid < 2 * half) {
          float* w = &RbU[(tid - half) * 20];
#pragma unroll
          for (int r = 0; r < 4; r++) *(float4*)&w[r * 4] = au[r];
        }
        __syncthreads();
        if (tid < half) {
          const float* p = &RbU[tid * 20];
#pragma unroll
          for (int r = 0; r < 4; r++) au[r] = f4add(au[r], *(const float4*)&p[r * 4]);
        }
        __syncthreads();
      }
      if (tid < 16) {
        float* w = &RbU[tid * 20];
#pragma unroll
        for (int r = 0; r < 4; r++) *(float4*)&w[r * 4] = au[r];
      }
      __syncthreads();
      {  // Mk store (+kb) -- WG-private data, plain stores
        const int row = tid >> 4, col = tid & 15;
        const int p = ((row >> 2) * 4 + (col >> 2)) * 20 + (row & 3) * 4 + (col & 3);
        Mk[(size_t)(row0 + row) * 8192 + t * 256 + c0 + col] = RbU[p] + kbs[col];
      }
      {  // gate dot (redundant per WG, from staged hsT)
        const int r = tid >> 4, seg = tid & 15;
        const int rot = ((seg & 3) << 2);
        const int rr = (r + rot) & 15;
        float s = 0.f;
#pragma unroll 8
        for (int kk2 = 0; kk2 < 32; ++kk2)
          s = fmaf(hsT[(seg * 32 + kk2) * 20 + rr], gWs[seg * 32 + kk2], s);
        s += __shfl_xor(s, 1); s += __shfl_xor(s, 2);
        s += __shfl_xor(s, 4); s += __shfl_xor(s, 8);
        if (seg == 0) gsh[r] = sigf(s + gb[0]);
      }
      __syncthreads();
      {  // keyr update + store (sc1)
        const int row = tid >> 4, col = tid & 15;
        if (t == 0) {
          st1a(&keyrT[(size_t)(c0 + col) * 512 + row0 + row], 0.f);
          if (cid == 0 && col == 0) st1a(&keyrT[(size_t)256 * 512 + row0 + row], 0.f);
        } else {
          float a = 0.f;
          const float* mkb = Mk + (size_t)(row0 + row) * 8192 + c0 + col;
#pragma unroll 4
          for (int tp = 0; tp < t; ++tp) a = fmaf(wws[row * 36 + tp], mkb[tp * 256], a);
          float g = gsh[row];
          st1a(&keyrT[(size_t)(c0 + col) * 512 + row0 + row], g * a);
          if (cid == 0 && col == 0)
            st1a(&keyrT[(size_t)256 * 512 + row0 + row], g * wc[(row0 + row) * 32 + t]);
        }
      }
      __syncthreads();
      if (tid == 0) {
        __builtin_amdgcn_fence(__ATOMIC_RELEASE, "agent");
        __hip_atomic_store(&ufl[rt * 16 + cid], t + 1, __ATOMIC_RELAXED, SCOPE_SYS);
      }
    }
  }

  // =================== y output (cid 0 WGs) ===================
  if (cid == 0) {
    if (tid < 16) {
      while (__hip_atomic_load(&gfl[rt * 16 + tid], __ATOMIC_RELAXED, SCOPE_SYS) < 33)
        __builtin_amdgcn_s_sleep(2);
    }
    __syncthreads();
    const int r = tid >> 4, seg = tid & 15;
    const float* hb = h + (size_t)(row0 + r) * 512 + seg * 32;
    float4 a = make_float4(0.f, 0.f, 0.f, 0.f);
#pragma unroll
    for (int i = 0; i < 16; ++i) {
      float2 hv = ld2a(hb + i * 2);
      const int k = seg * 32 + i * 2;
      a = f4fma(hv.x, *(const float4*)&yW[k * 4], a);
      a = f4fma(hv.y, *(const float4*)&yW[k * 4 + 4], a);
    }
#pragma unroll
    for (int off = 1; off <= 8; off <<= 1) {
      a.x += __shfl_xor(a.x, off);
      a.y += __shfl_xor(a.y, off);
      a.z += __shfl_xor(a.z, off);
      a.w += __shfl_xor(a.w, off);
    }
    if (seg == 0) {
      a.x += yb[0]; a.y += yb[1]; a.z += yb[2]; a.w += yb[3];
      const int row = row0 + r;
      out[row * 4 + 0] = a.x;
      out[row * 4 + 1] = a.y;
      out[row * 4 + 2] = a.z;
      out[row * 4 + 3] = a.w;
      int bi = 0; float bv = a.x;
      if (a.y > bv) { bv = a.y; bi = 1; }
      if (a.z > bv) { bv = a.z; bi = 2; }
      if (a.w > bv) { bv = a.w; bi = 3; }
      out[2048 + row] = (float)bi;
    }
  }
}

extern "C" void kernel_launch(void* const* d_in, const int* in_sizes, int n_in,
                              void* d_out, int out_size, void* d_ws, size_t ws_size,
                              hipStream_t stream)
{
  const float* x  = (const float*)d_in[0];
  const float* w1 = (const float*)d_in[1];
  const float* b1 = (const float*)d_in[2];
  const float* w2 = (const float*)d_in[3];
  const float* b2 = (const float*)d_in[4];
  const float* Wx = (const float*)d_in[5];
  const float* lb = (const float*)d_in[6];
  const float* kW = (const float*)d_in[7];
  const float* kb = (const float*)d_in[8];
  const float* gW = (const float*)d_in[9];
  const float* gb = (const float*)d_in[10];
  const float* yW = (const float*)d_in[11];
  const float* yb = (const float*)d_in[12];
  const float* cg = (const float*)d_in[13];
  const float* cb = (const float*)d_in[14];
  float* out = (float*)d_out;
  char* ws = (char*)d_ws;
  // ws layout:
  //  C1 @ [0, 33.55MB) (dead after k_gemm2; region reused):
  //    Mk    @ 0          (16.78MB) [512][32][256]
  //    warr  @ 16777216   (2MB)     [512][32][32]
  //    wc    @ 18874368   (64KB)    [512][32]
  //    keyrT @ 18939904   (527KB)   [257][512]
  //    h     @ 19466240   (1MB)     [512][512]
  //    flags @ 20514816   (4KB)     gfl[512], ufl[512]
  //  zp @ 33554432        (8.65MB)  [512][33][128]
  float* C1    = (float*)(ws);
  float* Mk    = (float*)(ws);
  float* warr  = (float*)(ws + 16777216);
  float* wcb   = (float*)(ws + 18874368);
  float* keyrT = (float*)(ws + 18939904);
  float* h     = (float*)(ws + 19466240);
  int*   gfl   = (int*)(ws + 20514816);
  int*   ufl   = gfl + 512;
  float* zp    = (float*)(ws + 33554432);

  hipLaunchKernelGGL(k_gemm1, dim3(512), dim3(256), 0, stream, x, w1, b1, C1);
  hipLaunchKernelGGL(k_gemm2, dim3(128), dim3(256), 0, stream, C1, w2, b2, zp);
  hipLaunchKernelGGL(k_gram, dim3(512), dim3(256), 0, stream, zp, warr, wcb, cg, cb);
  hipLaunchKernelGGL(k_zero, dim3(1), dim3(1024), 0, stream, gfl);

  void* ka[] = {(void*)&Wx, (void*)&lb, (void*)&kW, (void*)&kb, (void*)&gW, (void*)&gb,
                (void*)&yW, (void*)&yb, (void*)&warr, (void*)&wcb, (void*)&Mk,
                (void*)&keyrT, (void*)&h, (void*)&gfl, (void*)&ufl, (void*)&out};
  hipError_t e = hipLaunchCooperativeKernel((void*)k_scan, dim3(512), dim3(256), ka, 0, stream);
  if (e != hipSuccess) {
    // fallback: plain launch (512 WGs at 2/CU capacity are co-resident in practice)
    hipLaunchKernelGGL(k_scan, dim3(512), dim3(256), 0, stream,
                       Wx, lb, kW, kb, gW, gb, yW, yb, warr, wcb, Mk, keyrT, h, gfl, ufl, out);
  }
}

// Round 5
// 1320.091 us; speedup vs baseline: 2.1042x; 2.1042x over previous
//
#include <hip/hip_runtime.h>
#include <math.h>

__device__ __forceinline__ float sigf(float x) { return 1.0f / (1.0f + expf(-x)); }
__device__ __forceinline__ float4 f4fma(float s, float4 b, float4 a) {
  return make_float4(fmaf(s, b.x, a.x), fmaf(s, b.y, a.y), fmaf(s, b.z, a.z), fmaf(s, b.w, a.w));
}
__device__ __forceinline__ void wave_red2(float4& v) {
  v.x += __shfl_xor(v.x, 16); v.y += __shfl_xor(v.y, 16);
  v.z += __shfl_xor(v.z, 16); v.w += __shfl_xor(v.w, 16);
  v.x += __shfl_xor(v.x, 32); v.y += __shfl_xor(v.y, 32);
  v.z += __shfl_xor(v.z, 32); v.w += __shfl_xor(v.w, 32);
}

// ---------------- Encoder GEMM1: C = relu(X @ W + b) ----------------
// X:[16384,1024] W:[1024,512] C:[16384,512]; BK=16; cols split {tx*4, 64+tx*4}
__global__ __launch_bounds__(256) void k_gemm1(const float* __restrict__ X,
                                               const float* __restrict__ W,
                                               const float* __restrict__ Bv,
                                               float* __restrict__ C)
{
  const int K = 1024, N = 512;
  __shared__ float As[16][132];
  __shared__ float Bs[16][132];
  int tid = threadIdx.x;
  int bm = blockIdx.x >> 2;
  int bn = blockIdx.x & 3;
  int tx = tid & 15, ty = tid >> 4;
  int xr = tid & 127, xc8 = (tid >> 7) * 8;      // X staging
  int wk = tid >> 4, wc = (tid & 15) * 8;        // W staging
  const float* Xb = X + (size_t)(bm * 128 + xr) * K;
  const float* Wb = W + bn * 128 + wc;
  float acc[8][8];
#pragma unroll
  for (int i = 0; i < 8; i++)
#pragma unroll
    for (int j = 0; j < 8; j++) acc[i][j] = 0.f;

  for (int k0 = 0; k0 < K; k0 += 16) {
    float4 a0 = *(const float4*)(Xb + k0 + xc8);
    float4 a1 = *(const float4*)(Xb + k0 + xc8 + 4);
    float4 b0 = *(const float4*)(W + (size_t)(k0 + wk) * N + bn * 128 + wc);
    float4 b1 = *(const float4*)(W + (size_t)(k0 + wk) * N + bn * 128 + wc + 4);
    As[xc8 + 0][xr] = a0.x; As[xc8 + 1][xr] = a0.y;
    As[xc8 + 2][xr] = a0.z; As[xc8 + 3][xr] = a0.w;
    As[xc8 + 4][xr] = a1.x; As[xc8 + 5][xr] = a1.y;
    As[xc8 + 6][xr] = a1.z; As[xc8 + 7][xr] = a1.w;
    *(float4*)(&Bs[wk][wc]) = b0;
    *(float4*)(&Bs[wk][wc + 4]) = b1;
    __syncthreads();
#pragma unroll
    for (int kk = 0; kk < 16; kk++) {
      float a[8], b[8];
      *(float4*)(a)     = *(const float4*)(&As[kk][ty * 8]);
      *(float4*)(a + 4) = *(const float4*)(&As[kk][ty * 8 + 4]);
      *(float4*)(b)     = *(const float4*)(&Bs[kk][tx * 4]);
      *(float4*)(b + 4) = *(const float4*)(&Bs[kk][64 + tx * 4]);
#pragma unroll
      for (int i = 0; i < 8; i++)
#pragma unroll
        for (int j = 0; j < 8; j++) acc[i][j] = fmaf(a[i], b[j], acc[i][j]);
    }
    __syncthreads();
  }
  int crow0 = bm * 128 + ty * 8;
  int ccolA = bn * 128 + tx * 4;
  int ccolB = bn * 128 + 64 + tx * 4;
  float4 bvA = *(const float4*)(Bv + ccolA);
  float4 bvB = *(const float4*)(Bv + ccolB);
#pragma unroll
  for (int i = 0; i < 8; i++) {
    float4 vA = make_float4(acc[i][0] + bvA.x, acc[i][1] + bvA.y,
                            acc[i][2] + bvA.z, acc[i][3] + bvA.w);
    float4 vB = make_float4(acc[i][4] + bvB.x, acc[i][5] + bvB.y,
                            acc[i][6] + bvB.z, acc[i][7] + bvB.w);
    vA.x = vA.x > 0.f ? vA.x : 0.f; vA.y = vA.y > 0.f ? vA.y : 0.f;
    vA.z = vA.z > 0.f ? vA.z : 0.f; vA.w = vA.w > 0.f ? vA.w : 0.f;
    vB.x = vB.x > 0.f ? vB.x : 0.f; vB.y = vB.y > 0.f ? vB.y : 0.f;
    vB.z = vB.z > 0.f ? vB.z : 0.f; vB.w = vB.w > 0.f ? vB.w : 0.f;
    *(float4*)(&C[(size_t)(crow0 + i) * N + ccolA]) = vA;
    *(float4*)(&C[(size_t)(crow0 + i) * N + ccolB]) = vB;
  }
}

// ---------------- Encoder GEMM2 (unchanged from round 3) ----------------
__global__ __launch_bounds__(256) void k_gemm2(const float* __restrict__ A,
                                               const float* __restrict__ W,
                                               const float* __restrict__ Bv,
                                               float* __restrict__ zp)
{
  const int K = 512, N = 128;
  __shared__ float As[8][132];
  __shared__ float Bs[8][132];
  int tid = threadIdx.x;
  int bm = blockIdx.x;
  int tx = tid & 15, ty = tid >> 4;
  int arow = tid >> 1, acol4 = (tid & 1) * 4;
  int bkk = tid >> 5, bn4 = (tid & 31) * 4;
  const float* Ab = A + (size_t)(bm * 128) * K;
  float acc[8][8];
#pragma unroll
  for (int i = 0; i < 8; i++)
#pragma unroll
    for (int j2 = 0; j2 < 8; j2++) acc[i][j2] = 0.f;
  for (int k0 = 0; k0 < K; k0 += 8) {
    float4 av = *(const float4*)(Ab + (size_t)arow * K + k0 + acol4);
    float4 bv = *(const float4*)(W + (size_t)(k0 + bkk) * N + bn4);
    As[acol4 + 0][arow] = av.x;
    As[acol4 + 1][arow] = av.y;
    As[acol4 + 2][arow] = av.z;
    As[acol4 + 3][arow] = av.w;
    *(float4*)(&Bs[bkk][bn4]) = bv;
    __syncthreads();
#pragma unroll
    for (int kk = 0; kk < 8; kk++) {
      float a[8], b[8];
      *(float4*)(a)     = *(const float4*)(&As[kk][ty * 8]);
      *(float4*)(a + 4) = *(const float4*)(&As[kk][ty * 8 + 4]);
      *(float4*)(b)     = *(const float4*)(&Bs[kk][tx * 8]);
      *(float4*)(b + 4) = *(const float4*)(&Bs[kk][tx * 8 + 4]);
#pragma unroll
      for (int i = 0; i < 8; i++)
#pragma unroll
        for (int j2 = 0; j2 < 8; j2++) acc[i][j2] = fmaf(a[i], b[j2], acc[i][j2]);
    }
    __syncthreads();
  }
  int ccol0 = tx * 8;
#pragma unroll
  for (int i = 0; i < 8; i++) {
    int r = bm * 128 + ty * 8 + i;
    int b = r >> 5, tt = r & 31;
#pragma unroll
    for (int j2 = 0; j2 < 8; j2++) {
      zp[(size_t)b * (33 * 128) + tt * 128 + ccol0 + j2] = acc[i][j2] + Bv[ccol0 + j2];
    }
  }
}

// ---------------- Gram + softmax precompute (unchanged) ----------------
__global__ __launch_bounds__(256) void k_gram(const float* __restrict__ zp,
                                              float* __restrict__ warr,
                                              float* __restrict__ wc,
                                              const float* __restrict__ cgp,
                                              const float* __restrict__ cbp)
{
  __shared__ float zl[32][128];
  __shared__ float sg[32][32];
  int b = blockIdx.x, tid = threadIdx.x;
  const float* zb = zp + (size_t)b * (33 * 128);
  for (int i = tid; i < 32 * 128; i += 256) (&zl[0][0])[i] = zb[i];
  __syncthreads();
  for (int p = tid; p < 496; p += 256) {
    int t = 1;
    while (p >= t * (t + 1) / 2) t++;
    int tp = p - t * (t - 1) / 2;
    const float* za = &zl[t][0];
    const float* zc = &zl[tp][0];
    float s = 0.f;
#pragma unroll 4
    for (int c = 0; c < 128; c += 4) {
      s += za[c] * zc[c] + za[c + 1] * zc[c + 1] + za[c + 2] * zc[c + 2] + za[c + 3] * zc[c + 3];
    }
    sg[t][tp] = s;
  }
  __syncthreads();
  if (tid >= 1 && tid < 32) {
    int t = tid;
    float cg = cgp[0], cb = cbp[0];
    float m = -3.0e38f;
    for (int tp = 0; tp < t; tp++) m = fmaxf(m, sg[t][tp]);
    float se = 0.f;
    for (int tp = 0; tp < t; tp++) se += expf(sg[t][tp] - m);
    float inv = 1.0f / se;
    float wcs = 0.f;
    for (int tp = 0; tp < t; tp++) {
      float s = sg[t][tp];
      float w = expf(s - m) * inv;
      warr[(size_t)b * 1024 + t * 32 + tp] = w;
      wcs = fmaf(w, sigf(fmaf(s, cg, cb)), wcs);
    }
    wc[b * 32 + t] = wcs;
  }
}

// ---------------- per-step gates: h = act(keyr @ Wx + b) ----------------
// grid 512 (32 rowtiles x 16 hctiles), 256 thr, 2 WG/CU.
// tile 16r x 32hc x 3g; 16-way k-split; micro 8r x 4hc x 3g; in-wave shfl reduce.
__global__ __launch_bounds__(256) void k_gates(const float* __restrict__ Wx,
                                               const float* __restrict__ lb,
                                               const float* __restrict__ keyrT,
                                               float* __restrict__ h, int t)
{
  __shared__ float smem[6656];
  float* As = smem;            // [32][20]   keyr chunk [k][row]
  float* Bs = smem + 640;      // [32][100]  Wx chunk {i,c,o}
  float* Rb = smem;            // [4][16][100] per-wave partials (after staging dead)
  const int tid = threadIdx.x;
  const int rt = blockIdx.x >> 4;
  const int ct = blockIdx.x & 15;
  const int row0 = rt * 16;
  const int hc0 = ct * 32;

  if (t > 0) {
    const int ksub = tid >> 4;        // 0..15
    const int pos = tid & 15;
    const int rg = pos >> 3;          // rows rg*8..+7
    const int cg = pos & 7;           // hc cg*4..+3
    float4 aI[8], aC[8], aO[8];
#pragma unroll
    for (int r = 0; r < 8; r++) {
      aI[r] = make_float4(0.f, 0.f, 0.f, 0.f);
      aC[r] = make_float4(0.f, 0.f, 0.f, 0.f);
      aO[r] = make_float4(0.f, 0.f, 0.f, 0.f);
    }
    for (int c = 0; c < 8; ++c) {
      const int k0 = c * 32;
      if (c) __syncthreads();
      if (tid < 128) {
        const int kkA = tid >> 2, lA = (tid & 3) * 4;
        *(float4*)&As[kkA * 20 + lA] =
            *(const float4*)&keyrT[(size_t)(k0 + kkA) * 512 + row0 + lA];
      }
      {
        const int kkB = tid >> 3, lB = (tid & 7) * 4;
        const float* wrow = Wx + (size_t)(k0 + kkB) * 2048;
        *(float4*)&Bs[kkB * 100 + lB]      = *(const float4*)(wrow + hc0 + lB);
        *(float4*)&Bs[kkB * 100 + 32 + lB] = *(const float4*)(wrow + 1024 + hc0 + lB);
        *(float4*)&Bs[kkB * 100 + 64 + lB] = *(const float4*)(wrow + 1536 + hc0 + lB);
      }
      __syncthreads();
#pragma unroll
      for (int i = 0; i < 2; ++i) {
        const int kk = ksub * 2 + i;
        float a8[8];
        *(float4*)&a8[0] = *(const float4*)&As[kk * 20 + rg * 8];
        *(float4*)&a8[4] = *(const float4*)&As[kk * 20 + rg * 8 + 4];
        float4 bI = *(const float4*)&Bs[kk * 100 + cg * 4];
        float4 bC = *(const float4*)&Bs[kk * 100 + 32 + cg * 4];
        float4 bO = *(const float4*)&Bs[kk * 100 + 64 + cg * 4];
#pragma unroll
        for (int r = 0; r < 8; r++) {
          float a = a8[r];
          aI[r] = f4fma(a, bI, aI[r]);
          aC[r] = f4fma(a, bC, aC[r]);
          aO[r] = f4fma(a, bO, aO[r]);
        }
      }
    }
    if (ksub == 0) {  // tail k = 256
      float a8[8];
      *(float4*)&a8[0] = *(const float4*)&keyrT[(size_t)256 * 512 + row0 + rg * 8];
      *(float4*)&a8[4] = *(const float4*)&keyrT[(size_t)256 * 512 + row0 + rg * 8 + 4];
      const float* wrow = Wx + (size_t)256 * 2048;
      float4 bI = *(const float4*)(wrow + hc0 + cg * 4);
      float4 bC = *(const float4*)(wrow + 1024 + hc0 + cg * 4);
      float4 bO = *(const float4*)(wrow + 1536 + hc0 + cg * 4);
#pragma unroll
      for (int r = 0; r < 8; r++) {
        float a = a8[r];
        aI[r] = f4fma(a, bI, aI[r]);
        aC[r] = f4fma(a, bC, aC[r]);
        aO[r] = f4fma(a, bO, aO[r]);
      }
    }
    // in-wave reduction over the 4 ksubs resident in each wave
#pragma unroll
    for (int r = 0; r < 8; r++) { wave_red2(aI[r]); wave_red2(aC[r]); wave_red2(aO[r]); }
    __syncthreads();  // staging region dead -> Rb
    {
      const int wave = tid >> 6, lane = tid & 63;
      if (lane < 16) {
        float* w = &Rb[wave * 1600 + lane * 100];
#pragma unroll
        for (int r = 0; r < 8; r++) {
          *(float4*)&w[r * 12 + 0] = aI[r];
          *(float4*)&w[r * 12 + 4] = aC[r];
          *(float4*)&w[r * 12 + 8] = aO[r];
        }
      }
    }
    __syncthreads();
    // finalize: thread -> 2 h elements
    {
      const int r = tid >> 4;
      const int hc2 = (tid & 15) * 2;
      const int p = (r >> 3) * 8 + (hc2 >> 2);
      const int base = p * 100 + (r & 7) * 12;
      const int off = hc2 & 3;  // 0 or 2
      float sI0 = Rb[base + off]     + Rb[1600 + base + off]     + Rb[3200 + base + off]     + Rb[4800 + base + off];
      float sI1 = Rb[base + off + 1] + Rb[1600 + base + off + 1] + Rb[3200 + base + off + 1] + Rb[4800 + base + off + 1];
      float sC0 = Rb[base + 4 + off]     + Rb[1600 + base + 4 + off]     + Rb[3200 + base + 4 + off]     + Rb[4800 + base + 4 + off];
      float sC1 = Rb[base + 4 + off + 1] + Rb[1600 + base + 4 + off + 1] + Rb[3200 + base + 4 + off + 1] + Rb[4800 + base + 4 + off + 1];
      float sO0 = Rb[base + 8 + off]     + Rb[1600 + base + 8 + off]     + Rb[3200 + base + 8 + off]     + Rb[4800 + base + 8 + off];
      float sO1 = Rb[base + 8 + off + 1] + Rb[1600 + base + 8 + off + 1] + Rb[3200 + base + 8 + off + 1] + Rb[4800 + base + 8 + off + 1];
      float iv0 = sI0 + lb[hc0 + hc2],        iv1 = sI1 + lb[hc0 + hc2 + 1];
      float cv0 = sC0 + lb[1024 + hc0 + hc2], cv1 = sC1 + lb[1024 + hc0 + hc2 + 1];
      float ov0 = sO0 + lb[1536 + hc0 + hc2], ov1 = sO1 + lb[1536 + hc0 + hc2 + 1];
      float h0 = sigf(ov0) * tanhf(sigf(iv0) * tanhf(cv0));
      float h1 = sigf(ov1) * tanhf(sigf(iv1) * tanhf(cv1));
      *(float2*)&h[(size_t)(row0 + r) * 512 + hc0 + hc2] = make_float2(h0, h1);
    }
  } else {  // t == 0: h = act(bias)
    const int r = tid >> 4;
    const int hc2 = (tid & 15) * 2;
    float iv0 = lb[hc0 + hc2],        iv1 = lb[hc0 + hc2 + 1];
    float cv0 = lb[1024 + hc0 + hc2], cv1 = lb[1024 + hc0 + hc2 + 1];
    float ov0 = lb[1536 + hc0 + hc2], ov1 = lb[1536 + hc0 + hc2 + 1];
    float h0 = sigf(ov0) * tanhf(sigf(iv0) * tanhf(cv0));
    float h1 = sigf(ov1) * tanhf(sigf(iv1) * tanhf(cv1));
    *(float2*)&h[(size_t)(row0 + r) * 512 + hc0 + hc2] = make_float2(h0, h1);
  }
}

// ---------------- per-step update: keyw->Mk[t], gate, keyrT ----------------
// grid 512 (32 rowtiles x 16 coltiles), 256 thr, 2 WG/CU.
// tile 16r x 16c; 16-way k-split; micro 4r x 4c; row-major hs with broadcast A-reads.
__global__ __launch_bounds__(256) void k_update(const float* __restrict__ h,
                                                const float* __restrict__ kW,
                                                const float* __restrict__ kb,
                                                const float* __restrict__ gW,
                                                const float* __restrict__ gb,
                                                const float* __restrict__ warr,
                                                const float* __restrict__ wc,
                                                float* __restrict__ Mk,
                                                float* __restrict__ keyrT, int t)
{
  __shared__ float smem[10640];
  float* hs  = smem;           // [16][516] row-major h slice
  float* gWs = smem + 8256;    // [512]
  float* wws = smem + 8768;    // [16][36]
  float* gsh = smem + 9344;    // [16]
  float* kWs = smem + 9360;    // [32][20] chunk
  float* Rb  = smem + 9360;    // [4][16][20] partials (union with kWs)
  const int tid = threadIdx.x;
  const int rt = blockIdx.x >> 4;
  const int ct = blockIdx.x & 15;
  const int row0 = rt * 16;
  const int c0 = ct * 16;

  // stage hs (seg-rotated write order -> conflict-optimal), gWs, wws
  {
    const int r = tid >> 4, seg = tid & 15;
    const float* hrow = h + (size_t)(row0 + r) * 512 + seg * 32;
    float* hd = hs + r * 516 + seg * 32;
#pragma unroll
    for (int q = 0; q < 8; ++q) {
      const int qp = ((q + seg) & 7) * 4;
      *(float4*)&hd[qp] = *(const float4*)&hrow[qp];
    }
    if (tid < 128) *(float4*)&gWs[tid * 4] = *(const float4*)&gW[tid * 4];
    wws[r * 36 + seg]      = (seg < t)      ? warr[(size_t)(row0 + r) * 1024 + t * 32 + seg] : 0.f;
    wws[r * 36 + 16 + seg] = (16 + seg < t) ? warr[(size_t)(row0 + r) * 1024 + t * 32 + 16 + seg] : 0.f;
  }
  __syncthreads();

  // keyw GEMM: K=512 in 16 chunks of 32
  const int ksub = tid >> 4, pu = tid & 15, rgu = pu >> 2, cgu = pu & 3;
  float4 au[4];
#pragma unroll
  for (int r = 0; r < 4; r++) au[r] = make_float4(0.f, 0.f, 0.f, 0.f);
  for (int c = 0; c < 16; ++c) {
    if (c) __syncthreads();
    if (tid < 128) {
      const int kkW = tid >> 2, lW = (tid & 3) * 4;
      *(float4*)&kWs[kkW * 20 + lW] =
          *(const float4*)&kW[(size_t)(c * 32 + kkW) * 256 + c0 + lW];
    }
    __syncthreads();
#pragma unroll
    for (int i = 0; i < 2; ++i) {
      const int kk = ksub * 2 + i;
      float4 b4 = *(const float4*)&kWs[kk * 20 + cgu * 4];
      const int kidx = c * 32 + kk;
#pragma unroll
      for (int jj = 0; jj < 4; ++jj) {
        float a = hs[(rgu * 4 + jj) * 516 + kidx];
        au[jj] = f4fma(a, b4, au[jj]);
      }
    }
  }
  // in-wave reduce over 4 resident ksubs
#pragma unroll
  for (int r = 0; r < 4; r++) wave_red2(au[r]);
  __syncthreads();  // kWs dead -> Rb
  {
    const int wave = tid >> 6, lane = tid & 63;
    if (lane < 16) {
      float* w = &Rb[wave * 320 + lane * 20];
#pragma unroll
      for (int r = 0; r < 4; r++) *(float4*)&w[r * 4] = au[r];
    }
  }
  __syncthreads();
  // Mk write (+kb)
  {
    const int r = tid >> 4, cc = tid & 15;
    const int p = (r >> 2) * 4 + (cc >> 2);
    const int e = p * 20 + (r & 3) * 4 + (cc & 3);
    float v = Rb[e] + Rb[320 + e] + Rb[640 + e] + Rb[960 + e];
    Mk[(size_t)(row0 + r) * 8192 + t * 256 + c0 + cc] = v + kb[c0 + cc];
  }
  // gate dot
  {
    const int r = tid >> 4, seg = tid & 15;
    const float* hp = &hs[r * 516 + seg * 32];
    const float* gp = &gWs[seg * 32];
    float s = 0.f;
#pragma unroll 8
    for (int j = 0; j < 32; ++j) s = fmaf(hp[j], gp[j], s);
    s += __shfl_xor(s, 1); s += __shfl_xor(s, 2);
    s += __shfl_xor(s, 4); s += __shfl_xor(s, 8);
    if (seg == 0) gsh[r] = sigf(s + gb[0]);
  }
  __syncthreads();
  // keyr update (transposed store)
  {
    const int r = tid >> 4, cc = tid & 15;
    const int row = row0 + r;
    if (t == 0) {
      keyrT[(size_t)(c0 + cc) * 512 + row] = 0.f;
      if (ct == 0 && cc == 0) keyrT[(size_t)256 * 512 + row] = 0.f;
    } else {
      float a = 0.f;
      const float* mkb = Mk + (size_t)row * 8192 + c0 + cc;
      const float* wp = &wws[r * 36];
      for (int tp = 0; tp < t; ++tp) a = fmaf(wp[tp], mkb[tp * 256], a);
      float g = gsh[r];
      keyrT[(size_t)(c0 + cc) * 512 + row] = g * a;
      if (ct == 0 && cc == 0)
        keyrT[(size_t)256 * 512 + row] = g * wc[row * 32 + t];
    }
  }
}

// ---------------- final: y = h @ yW + yb, argmax ----------------
__global__ __launch_bounds__(256) void k_y(const float* __restrict__ h,
                                           const float* __restrict__ yW,
                                           const float* __restrict__ yb,
                                           float* __restrict__ out)
{
  int tid = threadIdx.x;
  int wave = tid >> 6, lane = tid & 63;
  int row = blockIdx.x * 4 + wave;
  float a0 = 0.f, a1 = 0.f, a2 = 0.f, a3 = 0.f;
  for (int k = lane; k < 512; k += 64) {
    float hv = h[(size_t)row * 512 + k];
    float4 w4 = *(const float4*)(yW + k * 4);
    a0 = fmaf(hv, w4.x, a0);
    a1 = fmaf(hv, w4.y, a1);
    a2 = fmaf(hv, w4.z, a2);
    a3 = fmaf(hv, w4.w, a3);
  }
#pragma unroll
  for (int off = 32; off > 0; off >>= 1) {
    a0 += __shfl_xor(a0, off);
    a1 += __shfl_xor(a1, off);
    a2 += __shfl_xor(a2, off);
    a3 += __shfl_xor(a3, off);
  }
  if (lane == 0) {
    a0 += yb[0]; a1 += yb[1]; a2 += yb[2]; a3 += yb[3];
    out[row * 4 + 0] = a0;
    out[row * 4 + 1] = a1;
    out[row * 4 + 2] = a2;
    out[row * 4 + 3] = a3;
    int bi = 0; float bv = a0;
    if (a1 > bv) { bv = a1; bi = 1; }
    if (a2 > bv) { bv = a2; bi = 2; }
    if (a3 > bv) { bv = a3; bi = 3; }
    out[2048 + row] = (float)bi;
  }
}

extern "C" void kernel_launch(void* const* d_in, const int* in_sizes, int n_in,
                              void* d_out, int out_size, void* d_ws, size_t ws_size,
                              hipStream_t stream)
{
  const float* x  = (const float*)d_in[0];
  const float* w1 = (const float*)d_in[1];
  const float* b1 = (const float*)d_in[2];
  const float* w2 = (const float*)d_in[3];
  const float* b2 = (const float*)d_in[4];
  const float* Wx = (const float*)d_in[5];
  const float* lb = (const float*)d_in[6];
  const float* kW = (const float*)d_in[7];
  const float* kb = (const float*)d_in[8];
  const float* gW = (const float*)d_in[9];
  const float* gb = (const float*)d_in[10];
  const float* yW = (const float*)d_in[11];
  const float* yb = (const float*)d_in[12];
  const float* cg = (const float*)d_in[13];
  const float* cb = (const float*)d_in[14];
  float* out = (float*)d_out;
  char* ws = (char*)d_ws;
  // ws layout:
  //  C1 @ [0, 33.55MB)  (dead after k_gemm2; region reused below)
  //    Mk    @ 0          (16.78MB)  [512][32][256] f32
  //    warr  @ 16777216   (2MB)      [512][32][32]  f32
  //    wc    @ 18874368   (64KB)     [512][32]      f32
  //    keyrT @ 18939904   (526KB)    [257][512]     f32 (transposed)
  //    h     @ 19466240   (1MB)      [512][512]     f32
  //  zp @ 33554432        (8.65MB)   [512][33][128] f32
  float* C1    = (float*)(ws);
  float* Mk    = (float*)(ws);
  float* warr  = (float*)(ws + 16777216);
  float* wcb   = (float*)(ws + 18874368);
  float* keyrT = (float*)(ws + 18939904);
  float* h     = (float*)(ws + 19466240);
  float* zp    = (float*)(ws + 33554432);

  hipLaunchKernelGGL(k_gemm1, dim3(512), dim3(256), 0, stream, x, w1, b1, C1);
  hipLaunchKernelGGL(k_gemm2, dim3(128), dim3(256), 0, stream, C1, w2, b2, zp);
  hipLaunchKernelGGL(k_gram, dim3(512), dim3(256), 0, stream, zp, warr, wcb, cg, cb);
  for (int t = 0; t <= 32; t++) {
    hipLaunchKernelGGL(k_gates, dim3(512), dim3(256), 0, stream, Wx, lb, keyrT, h, t);
    if (t < 32) {
      hipLaunchKernelGGL(k_update, dim3(512), dim3(256), 0, stream,
                         h, kW, kb, gW, gb, warr, wcb, Mk, keyrT, t);
    }
  }
  hipLaunchKernelGGL(k_y, dim3(128), dim3(256), 0, stream, h, yW, yb, out);
}